// Round 9
// baseline (1222.550 us; speedup 1.0000x reference)
//
#include <hip/hip_runtime.h>

#define S 128
#define NEGF (-1e30f)
#define MAXB 16
#define NT 512
#define STAGE_SZ 8064   // max 2*(126-w)*(w|1) = 7938 at w=63
// sc is read row- and column-wise: XOR-swizzle columns (r4-verified).
#define SC(r, c) sc[r][(c) ^ ((r) & 31)]

// Static device workspace (d_ws proved unreliable in rounds 0-2).
__device__ float g_ssw[MAXB * S * S];   // sibling spans, [b][width][start]
__device__ float g_logZ[MAXB];
__device__ float g_partials[512];

__device__ __forceinline__ bool mask_at(const unsigned char* m, int i, bool by) {
  return by ? (m[i] != 0) : (((const int*)m)[i] != 0);
}

// global -> LDS DMA, 4B/lane: dest = uniform base + lane*4 (r6-r8 verified).
__device__ __forceinline__ void gload_lds4(const float* g, float* l) {
  __builtin_amdgcn_global_load_lds(
      (const __attribute__((address_space(1))) unsigned int*)g,
      (__attribute__((address_space(3))) unsigned int*)l, 4, 0, 0);
}

template <int CTRL>
__device__ __forceinline__ float dpp_f(float x) {
  int i = __float_as_int(x);
  return __int_as_float(__builtin_amdgcn_update_dpp(i, i, CTRL, 0xF, 0xF, false));
}
// Folds across p=2^lp adjacent lanes (groups lane-aligned). After xor1/xor2
// each 4-group is uniform, so mirror8 (0x141) == xor4, mirror16 (0x140) == xor8.
__device__ __forceinline__ float foldmax(float m, int lp) {
  if (lp >= 1) m = fmaxf(m, dpp_f<0xB1>(m));
  if (lp >= 2) m = fmaxf(m, dpp_f<0x4E>(m));
  if (lp >= 3) m = fmaxf(m, dpp_f<0x141>(m));
  if (lp >= 4) m = fmaxf(m, dpp_f<0x140>(m));
  return m;
}
__device__ __forceinline__ float foldsum(float s, int lp) {
  if (lp >= 1) s += dpp_f<0xB1>(s);
  if (lp >= 2) s += dpp_f<0x4E>(s);
  if (lp >= 3) s += dpp_f<0x141>(s);
  if (lp >= 4) s += dpp_f<0x140>(s);
  return s;
}

// Two-pass group-lse: pass 1 loads chunk into static regs + max; DPP-fold max;
// pass 2 exp-sums from registers; DPP-fold sum. Finite NEGF sentinel => no NaN.
template <int CH, typename F>
__device__ __forceinline__ float lse_chunk(F val, int i0, int ntrip,
                                           float base, bool has_base, int lp) {
  float v[CH];
  float lm0 = has_base ? base : NEGF, lm1 = NEGF;
#pragma unroll
  for (int u = 0; u < CH; ++u) {
    if (u < ntrip) {
      v[u] = val(i0 + u);
      if (u & 1) lm1 = fmaxf(lm1, v[u]); else lm0 = fmaxf(lm0, v[u]);
    }
  }
  float m = foldmax(fmaxf(lm0, lm1), lp);
  float s0 = has_base ? __expf(base - m) : 0.f, s1 = 0.f, s2 = 0.f, s3 = 0.f;
#pragma unroll
  for (int u = 0; u < CH; ++u) {
    if (u < ntrip) {
      float e = __expf(v[u] - m);
      if ((u & 3) == 0) s0 += e;
      else if ((u & 3) == 1) s1 += e;
      else if ((u & 3) == 2) s2 += e;
      else s3 += e;
    }
  }
  float s = foldsum((s0 + s1) + (s2 + s3), lp);
  return __logf(s) + m;
}

// One block (512 thr) per batch element. Per width w:
//   ph1: ir (threads 0-255) / il (256-511), p2-lane-split tasks
//   B1; DMA sib(w+1) -> stage; ph2: cl / cr; B2 (drains DMA)
//   slot3: enrich stage(w+1) += SSW (half 0) || slr S(*,*+w+1) (half 1); B3
__global__ __launch_bounds__(NT) void dp_kernel(
    const float* __restrict__ arc,          // [B,S,S] s_arc[b,dep,head]
    const float* __restrict__ sib,          // [B,S,S,S] s_sib[b,dep,head,sib]
    const unsigned char* __restrict__ mask) // [B,S]
{
  __shared__ float si[S][S];
  __shared__ float sc[S][S];
  __shared__ float stage[STAGE_SZ];
  __shared__ int len_sh, cnt0_sh;

  const int b = blockIdx.x;
  const int tid = threadIdx.x;
  const float* arc_b = arc + (size_t)b * S * S;      // arc_b[dep*S+head]
  const float* SBraw = sib + (size_t)b * S * S * S;  // SBraw[dep][head][sib]
  float* ssw = g_ssw + (size_t)b * S * S;

  if (tid == 0) { len_sh = 0; cnt0_sh = 0; }
  __syncthreads();
  if (tid < S && mask[tid] != 0) atomicAdd(&cnt0_sh, 1);  // byte-interp of row 0
  for (int i = tid; i < S * S; i += NT) {
    (&si[0][0])[i] = NEGF;
    (&sc[0][0])[i] = NEGF;
  }
  __syncthreads();
  const bool bytes = (cnt0_sh >= 64);  // bool bytes: ~127 nonzero; int32: ~31
  if (tid < S) {
    SC(tid, tid) = 0.0f;               // width-0 complete spans
    if (mask_at(mask, b * S + tid, bytes)) atomicAdd(&len_sh, 1);
  }
  if (tid >= 1 && tid < S - 1) ssw[S + tid] = 0.0f;  // S(k,k+1) = 0 bootstrap
  __syncthreads();
  const int len = min(len_sh, S - 1);
  if (tid == 0) g_logZ[b] = 0.0f;      // len==0 fallback

  const int half = tid >> 8;           // 0 / 1 (wave-aligned)
  const int hloc = tid & 255;

  for (int w = 1; w < S; ++w) {
    const int nk = S - w, n1 = w - 1;
    const int rlP = n1 | 1;
    const int lp2 = (nk <= 16) ? 4 : (nk <= 32) ? 3 : (nk <= 64) ? 2 : 1;
    const int p2 = 1 << lp2;
    const int q = hloc & (p2 - 1);
    const int k = hloc >> lp2;
    const int kw = k + w;

    // ================= phase 1: ir (half 0) / il (half 1) =================
    if (k < nk) {
      float bm, arcv;
      const float *pa, *pt;
      if (half == 0) {        // I(k -> kw): base j=0; siblings x=k+1..kw-1
        bm = SC(k, k) + SC(kw, k + 1);
        arcv = arc_b[kw * S + k];
        pa = &si[k][k + 1];
        pt = &stage[(k >= 1 ? k - 1 : 0) * rlP];
      } else {                // I(kw -> k): base j=w-1; siblings x=k+1..kw-1
        bm = (k == 0) ? 0.0f : (SC(kw, kw) + SC(k, kw - 1));
        arcv = arc_b[k * S + kw];
        pa = &si[kw][k + 1];
        pt = &stage[((nk - 1) + (k >= 1 ? k - 1 : 0)) * rlP];
      }
      int i0 = 0, ntrip = 0;
      if (k >= 1 && n1 > 0) {
        const int ch = n1 >> lp2;
        i0 = q * ch;
        ntrip = ((q == p2 - 1) ? n1 : i0 + ch) - i0;
      }
      const int ntmax = n1 - (p2 - 1) * (n1 >> lp2);
      auto val = [&](int i) { return pa[i] + pt[i]; };
      float r = (ntmax <= 8)
          ? lse_chunk<8>(val, i0, ntrip, bm, q == 0, lp2)
          : lse_chunk<32>(val, i0, ntrip, bm, q == 0, lp2);
      r += arcv;
      if (q == 0) {
        if (half == 0) si[k][kw] = r; else si[kw][k] = r;
      }
    }
    __syncthreads();   // B1: si(w) final; stage(w) dead

    // ========== DMA sib stage for width w+1 (drains at B2) ==========
    const int wn = w + 1;
    if (wn < S) {
      const int nk2 = S - wn;
      const int R = 2 * (nk2 - 1);
      const int rowlen = wn - 1;        // = w
      const int rlP2 = rowlen | 1;
      const int l = tid & 63;
      for (int r = (tid >> 6); r < R; r += 8) {
        const int buf = r & 1;
        const int kr = 1 + (r >> 1);
        const int kw2 = kr + wn;
        const size_t srcoff = (buf == 0)
            ? ((size_t)(kw2 * S + kr) * S + (kr + 1))   // ir: sib[dep=kw][head=k][x]
            : ((size_t)(kr * S + kw2) * S + (kr + 1));  // il: sib[dep=k][head=kw][x]
        const float* src = SBraw + srcoff;
        float* dst = &stage[(buf * (nk2 - 1) + (kr - 1)) * rlP2];
        if (l < rowlen) gload_lds4(src + l, dst);
        if (rowlen > 64 && l < rowlen - 64) gload_lds4(src + 64 + l, dst + 64);
      }
    }

    // ================= phase 2: cl (half 0) / cr (half 1) =================
    if (k < nk) {
      const int n2 = w;
      const int ch = n2 >> lp2;
      const int i0 = q * ch;
      const int ntrip = ((q == p2 - 1) ? n2 : i0 + ch) - i0;
      const int ntmax = n2 - (p2 - 1) * ch;
      if (half == 0) {        // cl: C(kw->k) over x=0..w-1: sc[k+x][k]+si[kw][k+x]
        const float* pB = &si[kw][k];
        auto val = [&](int i) { return SC(k + i, k) + pB[i]; };
        float r = (ntmax <= 8)
            ? lse_chunk<8>(val, i0, ntrip, NEGF, false, lp2)
            : lse_chunk<32>(val, i0, ntrip, NEGF, false, lp2);
        if (q == 0) SC(kw, k) = r;
      } else {                // cr: C(k->kw) over y=1..w: si[k][k+y]+sc[k+y][kw]
        const float* pA = &si[k][k + 1];
        auto val = [&](int i) { return pA[i] + SC(k + 1 + i, kw); };
        float r = (ntmax <= 8)
            ? lse_chunk<8>(val, i0, ntrip, NEGF, false, lp2)
            : lse_chunk<32>(val, i0, ntrip, NEGF, false, lp2);
        if (q == 0) {
          if (k == 0) {
            // single-root kill: C(0->w) survives only at w == len
            if (w == len) g_logZ[b] = r;
            SC(0, w) = (w == len) ? r : NEGF;
          } else {
            SC(k, kw) = r;
          }
        }
      }
    }
    __syncthreads();   // B2: sc(w) final; DMA(w+1) landed

    // ==== slot3: enrich stage(w+1) (half 0)  ||  slr S(*, *+w+1) (half 1) ====
    if (wn < S) {
      const int nk3 = S - wn;
      if (half == 1) {        // slr(wn): k3 in [1, nk3)
        const int lp3 = (nk3 <= 16) ? 4 : (nk3 <= 32) ? 3 : (nk3 <= 64) ? 2 : 1;
        const int p3 = 1 << lp3;
        const int q3 = hloc & (p3 - 1);
        const int k3 = hloc >> lp3;
        if (k3 >= 1 && k3 < nk3) {
          const int n3 = wn;
          const int ch3 = n3 >> lp3;
          const int i0 = q3 * ch3;
          const int ntrip = ((q3 == p3 - 1) ? n3 : i0 + ch3) - i0;
          const int ntmax = n3 - (p3 - 1) * ch3;
          auto val = [&](int i) { return SC(k3, k3 + i) + SC(k3 + wn, k3 + 1 + i); };
          float r = (ntmax <= 8)
              ? lse_chunk<8>(val, i0, ntrip, NEGF, false, lp3)
              : lse_chunk<32>(val, i0, ntrip, NEGF, false, lp3);
          if (q3 == 0) ssw[wn * S + k3] = r;
        }
      } else {                // enrich: stage(wn)[row][i] += SSW term
        const int rows1 = nk3 - 1;
        const int rowlen = wn - 1;       // = w
        const int rlP2 = rowlen | 1;
        if (rows1 > 0) {
          const int rows = 2 * rows1;    // <= 250 <= 256
          int lrsp = 0;
          while ((rows << (lrsp + 1)) <= 256 && lrsp < 4) ++lrsp;
          const int rsp = 1 << lrsp;
          const int rowid = hloc >> lrsp;
          const int e = hloc & (rsp - 1);
          if (rowid < rows) {
            const int typ = (rowid >= rows1) ? 1 : 0;
            const int kk2 = rowid - typ * rows1;
            const int kr = kk2 + 1;
            float* st = &stage[(typ * rows1 + kk2) * rlP2];
            const int ch = rowlen >> lrsp;
            const int i0 = e * ch;
            const int ie = (e == rsp - 1) ? rowlen : i0 + ch;
            if (typ == 0) {
              // ir row k: += SSW[wn-1-i][kr+1+i] (anti-diagonal)
              const float* pw_ = ssw + (wn - 1) * S + (kr + 1);
#pragma unroll 8
              for (int i = i0; i < ie; ++i) st[i] += pw_[i * (1 - S)];
            } else {
              // il row k: += SSW[1+i][kr] (column)
              const float* pw_ = ssw + S + kr;
#pragma unroll 8
              for (int i = i0; i < ie; ++i) st[i] += pw_[i * S];
            }
          }
        }
      }
    }
    __syncthreads();   // B3: stage(w+1) complete
  }
}

// Gather score: masked arc scores + positive-sibling scores, count mask.
__global__ __launch_bounds__(256) void score_kernel(
    const float* __restrict__ arc, const float* __restrict__ sib,
    const unsigned char* __restrict__ mask, const int* __restrict__ arcs,
    const int* __restrict__ sibs, int B)
{
  __shared__ bool bytes_sh;
  if (threadIdx.x == 0) {
    int c = 0;
    for (int i = 0; i < S; ++i) c += (mask[i] != 0);
    bytes_sh = (c >= 64);
  }
  __syncthreads();
  const bool bytes = bytes_sh;

  const int total = B * S * S;
  int tid = blockIdx.x * blockDim.x + threadIdx.x;
  float sum = 0.f, cnt = 0.f;
  for (int e = tid; e < total; e += gridDim.x * blockDim.x) {
    int sv = sibs[e];
    if (sv > 0) sum += sib[(size_t)e * S + sv];
    if ((e & (S - 1)) == 0) {           // once per (b,i)
      int bi = e >> 7;
      if (mask_at(mask, bi, bytes)) { sum += arc[(size_t)bi * S + arcs[bi]]; cnt += 1.f; }
    }
  }
  __shared__ float rs[256], rc[256];
  rs[threadIdx.x] = sum; rc[threadIdx.x] = cnt;
  __syncthreads();
  for (int off = 128; off; off >>= 1) {
    if (threadIdx.x < off) {
      rs[threadIdx.x] += rs[threadIdx.x + off];
      rc[threadIdx.x] += rc[threadIdx.x + off];
    }
    __syncthreads();
  }
  if (threadIdx.x == 0) {
    g_partials[blockIdx.x * 2]     = rs[0];
    g_partials[blockIdx.x * 2 + 1] = rc[0];
  }
}

__global__ __launch_bounds__(256) void final_kernel(int B, float* __restrict__ out)
{
  __shared__ float rs[256], rc[256];
  int t = threadIdx.x;
  float v = -g_partials[t * 2];
  float c = g_partials[t * 2 + 1];
  if (t < B) v += g_logZ[t];
  rs[t] = v; rc[t] = c;
  __syncthreads();
  for (int off = 128; off; off >>= 1) {
    if (t < off) { rs[t] += rs[t + off]; rc[t] += rc[t + off]; }
    __syncthreads();
  }
  if (t == 0) out[0] = rs[0] / rc[0];   // (logZ - score) / mask.sum()
}

extern "C" void kernel_launch(void* const* d_in, const int* in_sizes, int n_in,
                              void* d_out, int out_size, void* d_ws, size_t ws_size,
                              hipStream_t stream) {
  const float* s_arc = (const float*)d_in[0];
  const float* s_sib = (const float*)d_in[1];
  const unsigned char* mask = (const unsigned char*)d_in[2];
  const int* arcs = (const int*)d_in[3];
  const int* sibs = (const int*)d_in[4];
  int B = in_sizes[0] / (S * S);
  if (B > MAXB) B = MAXB;

  score_kernel<<<dim3(256), dim3(256), 0, stream>>>(s_arc, s_sib, mask, arcs, sibs, B);
  dp_kernel<<<dim3(B), dim3(NT), 0, stream>>>(s_arc, s_sib, mask);
  final_kernel<<<dim3(1), dim3(256), 0, stream>>>(B, (float*)d_out);
}

// Round 10
// 829.910 us; speedup vs baseline: 1.4731x; 1.4731x over previous
//
#include <hip/hip_runtime.h>

#define S 128
#define NEGF (-1e30f)
#define MAXB 16
#define NT 512
#define STAGE_SZ 8064     // max over wn of 2*(S-wn-1)*((wn-1)|1)  (wn=63)
#define PKB 700000        // per-batch packed sib floats (>= 698250 exact)

// Static device workspace (d_ws proved unreliable in rounds 0-2).
__device__ float g_ssw[MAXB * S * S];        // sibling spans, [b][width][start]
__device__ float g_spk[(size_t)MAXB * PKB];  // packed sib, [b][wn][typ][k-1][i]
__device__ float g_logZ[MAXB];
__device__ float g_partials[512];

__device__ __forceinline__ bool mask_at(const unsigned char* m, int i, bool by) {
  return by ? (m[i] != 0) : (((const int*)m)[i] != 0);
}

// global -> LDS DMA, 4B/lane: dest = wave-uniform base + lane*4 (r6-r8 verified).
__device__ __forceinline__ void gload_lds4(const float* g, float* l) {
  __builtin_amdgcn_global_load_lds(
      (const __attribute__((address_space(1))) unsigned int*)g,
      (__attribute__((address_space(3))) unsigned int*)l, 4, 0, 0);
}

// Online-lse pieces (r8-verified). Finite NEGF sentinel => no NaN.
__device__ __forceinline__ void upd(float& m, float& s, float v) {
  float mn = fmaxf(m, v);
  s = s * __expf(m - mn) + __expf(v - mn);
  m = mn;
}
__device__ __forceinline__ void fold(float& m0, float& s0, float m1, float s1) {
  float mn = fmaxf(m0, m1);
  s0 = s0 * __expf(m0 - mn) + s1 * __expf(m1 - mn);
  m0 = mn;
}
template <int CTRL>
__device__ __forceinline__ float dpp_f(float x) {
  int i = __float_as_int(x);
  return __int_as_float(__builtin_amdgcn_update_dpp(i, i, CTRL, 0xF, 0xF, false));
}
// Cross-lane (m,s) fold over p=2^lp lane-aligned groups. Levels: xor1(0xB1),
// xor2(0x4E), then mirror8(0x141)/mirror16(0x140) act as xor4/xor8 since the
// sub-blocks are uniform after the earlier levels (r5/r9-verified ctrls).
__device__ __forceinline__ void xfold(float& m, float& s, int lp) {
  if (lp >= 1) { float mo = dpp_f<0xB1>(m),  so = dpp_f<0xB1>(s);  fold(m, s, mo, so); }
  if (lp >= 2) { float mo = dpp_f<0x4E>(m),  so = dpp_f<0x4E>(s);  fold(m, s, mo, so); }
  if (lp >= 3) { float mo = dpp_f<0x141>(m), so = dpp_f<0x141>(s); fold(m, s, mo, so); }
  if (lp >= 4) { float mo = dpp_f<0x140>(m), so = dpp_f<0x140>(s); fold(m, s, mo, so); }
}
// Online 4-accumulator serial lse over n elements starting at i0, then DPP fold.
template <typename F>
__device__ __forceinline__ float lse_run(F val, int i0, int n,
                                         float base, bool has_base, int lp) {
  float m0 = has_base ? base : NEGF, s0 = has_base ? 1.f : 0.f;
  float m1 = NEGF, s1 = 0.f, m2 = NEGF, s2 = 0.f, m3 = NEGF, s3 = 0.f;
  int i = i0;
  const int ie = i0 + n;
#pragma unroll 2
  for (; i + 4 <= ie; i += 4) {
    upd(m0, s0, val(i));
    upd(m1, s1, val(i + 1));
    upd(m2, s2, val(i + 2));
    upd(m3, s3, val(i + 3));
  }
  for (; i < ie; ++i) upd(m0, s0, val(i));
  fold(m0, s0, m1, s1); fold(m2, s2, m3, s3); fold(m0, s0, m2, s2);
  xfold(m0, s0, lp);
  return __logf(s0) + m0;
}
__device__ __forceinline__ int lp_for(int nk) {
  return (nk <= 16) ? 4 : (nk <= 32) ? 3 : (nk <= 64) ? 2 : 1;
}

// One-time repack of s_sib into the per-width stage layout (all 256 CUs):
// dst[b][OFF(wn) + (typ*(nk2-1) + (k-1))*rlP + i] = sib[b][dep][head][k+1+i]
__global__ __launch_bounds__(256) void pack_kernel(const float* __restrict__ sib) {
  const int wn = 2 + (blockIdx.x % 126);
  const int b = blockIdx.x / 126;
  const int nk2 = S - wn;
  const int rows1 = nk2 - 1;
  if (rows1 <= 0) return;
  const int rowlen = wn - 1;
  const int rlP = rowlen | 1;
  int off = 0;
  for (int v = 2; v < wn; ++v) off += 2 * (S - v - 1) * ((v - 1) | 1);
  const float* SBraw = sib + (size_t)b * S * S * S;   // [dep][head][sib]
  float* dst = g_spk + (size_t)b * PKB + off;
  const int lane5 = threadIdx.x & 31;
  const int R = 2 * rows1;
  for (int r = (threadIdx.x >> 5); r < R; r += 8) {
    const int typ = (r >= rows1) ? 1 : 0;
    const int kr = (r - typ * rows1) + 1;
    const int kw2 = kr + wn;
    const size_t srcoff = (typ == 0)
        ? ((size_t)(kw2 * S + kr) * S + (kr + 1))    // ir: sib[dep=kw][head=k][x]
        : ((size_t)(kr * S + kw2) * S + (kr + 1));   // il: sib[dep=k][head=kw][x]
    const float* src = SBraw + srcoff;
    float* d = dst + r * rlP;
    for (int i = lane5; i < rowlen; i += 32) d[i] = src[i];
  }
}

// One block (512 thr) per batch element. Per width w (3 barriers):
//   ph1: ir (tid 0-255) || il (256-511), p-lane-split online lse
//   B1; linear DMA stage(w+1) from g_spk
//   ph2: cl || cr
//   B2 (drains DMA); slot3: slr(w+1) (fam0) || enrich stage(w+1) += SSW (fam1)
//   B3
__global__ __launch_bounds__(NT) void dp_kernel(
    const float* __restrict__ arc,          // [B,S,S] s_arc[b,dep,head]
    const unsigned char* __restrict__ mask) // [B,S]
{
  __shared__ float si[S][S];
  __shared__ float sc[S][S];
  __shared__ float stage[STAGE_SZ];
  __shared__ int len_sh, cnt0_sh;

  const int b = blockIdx.x;
  const int tid = threadIdx.x;
  const float* arc_b = arc + (size_t)b * S * S;      // arc_b[dep*S+head]
  const float* spk_b = g_spk + (size_t)b * PKB;
  float* ssw = g_ssw + (size_t)b * S * S;

  if (tid == 0) { len_sh = 0; cnt0_sh = 0; }
  __syncthreads();
  if (tid < S && mask[tid] != 0) atomicAdd(&cnt0_sh, 1);  // byte-interp of row 0
  for (int i = tid; i < S * S; i += NT) {
    (&si[0][0])[i] = NEGF;
    (&sc[0][0])[i] = NEGF;
  }
  __syncthreads();
  const bool bytes = (cnt0_sh >= 64);  // bool bytes: ~127 nonzero; int32: ~31
  if (tid < S) {
    sc[tid][tid] = 0.0f;               // width-0 complete spans
    if (mask_at(mask, b * S + tid, bytes)) atomicAdd(&len_sh, 1);
  }
  if (tid >= 1 && tid < S - 1) ssw[S + tid] = 0.0f;  // S(k,k+1) = 0 bootstrap
  __syncthreads();
  const int len = min(len_sh, S - 1);
  if (tid == 0) g_logZ[b] = 0.0f;      // len==0 fallback

  const int fam = tid >> 8;            // 0 / 1 (wave-aligned)
  const int floc = tid & 255;
  int spk_off = 0;                     // running OFF(wn), wn = w+1

  for (int w = 1; w < S; ++w) {
    const int nk = S - w, n1 = w - 1;
    const int rlP = n1 | 1;
    const int lp = lp_for(nk);
    const int p = 1 << lp;
    const int q = floc & (p - 1);
    const int k = floc >> lp;
    const int kw = k + w;

    // ================= phase 1: ir (fam 0) || il (fam 1) =================
    if (k < nk) {
      float bm, arcv;
      const float *pa, *pt;
      if (fam == 0) {        // I(k -> kw): base j=0; siblings x=k+1..kw-1
        bm = sc[k][k] + sc[kw][k + 1];
        arcv = arc_b[kw * S + k];
        pa = &si[k][k + 1];
        pt = &stage[(k >= 1 ? k - 1 : 0) * rlP];
      } else {               // I(kw -> k): base j=w-1; siblings x=k+1..kw-1
        bm = (k == 0) ? 0.0f : (sc[kw][kw] + sc[k][kw - 1]);
        arcv = arc_b[k * S + kw];
        pa = &si[kw][k + 1];
        pt = &stage[((nk - 1) + (k >= 1 ? k - 1 : 0)) * rlP];
      }
      int i0 = 0, ntrip = 0;
      if (k >= 1 && n1 > 0) {
        const int ch = n1 >> lp;
        i0 = q * ch;
        ntrip = ((q == p - 1) ? n1 : i0 + ch) - i0;
      }
      auto val = [&](int i) { return pa[i] + pt[i]; };
      float r = lse_run(val, i0, ntrip, bm, q == 0, lp) + arcv;
      if (q == 0) {
        if (fam == 0) si[k][kw] = r; else si[kw][k] = r;
      }
    }
    __syncthreads();   // B1: si(w) final; stage(w) dead

    // ===== linear DMA: packed sib block for width w+1 (drains at B2) =====
    const int wn = w + 1;
    if (wn < S) {
      const int rows1n = S - wn - 1;
      const int T = 2 * rows1n * ((wn - 1) | 1);
      const float* src = spk_b + spk_off;
      const int wv = tid >> 6, l = tid & 63;
      for (int c = wv; c * 64 < T; c += 8) {
        const int e = c * 64 + l;
        if (e < T) gload_lds4(src + e, &stage[c * 64]);
      }
    }

    // ================= phase 2: cl (fam 0) || cr (fam 1) =================
    if (k < nk) {
      const int ch = w >> lp;
      const int i0 = q * ch;
      const int ntrip = ((q == p - 1) ? w : i0 + ch) - i0;
      if (fam == 0) {        // cl: C(kw->k) over x=0..w-1: sc[k+x][k]+si[kw][k+x]
        const float* pA = &sc[k][k];      // pA[i*S] = sc[k+i][k]
        const float* pB = &si[kw][k];
        auto val = [&](int i) { return pA[i * S] + pB[i]; };
        float r = lse_run(val, i0, ntrip, NEGF, false, lp);
        if (q == 0) sc[kw][k] = r;
      } else {               // cr: C(k->kw) over y=1..w: si[k][k+y]+sc[k+y][kw]
        const float* pA = &si[k][k + 1];
        const float* pB = &sc[k + 1][kw]; // pB[i*S] = sc[k+1+i][kw]
        auto val = [&](int i) { return pA[i] + pB[i * S]; };
        float r = lse_run(val, i0, ntrip, NEGF, false, lp);
        if (q == 0) {
          if (k == 0) {
            // single-root kill: C(0->w) survives only at w == len
            if (w == len) g_logZ[b] = r;
            sc[0][w] = (w == len) ? r : NEGF;
          } else {
            sc[k][kw] = r;
          }
        }
      }
    }
    __syncthreads();   // B2: sc(w) final; DMA(w+1) landed

    // ==== slot3: slr S(*,*+wn) (fam 0) || enrich stage(wn) += SSW (fam 1) ====
    if (wn < S) {
      const int nk3 = S - wn;
      if (fam == 0) {        // slr(wn): k3 in [1, nk3); reads sc widths <= w
        const int lp3 = lp_for(nk3);
        const int p3 = 1 << lp3;
        const int q3 = floc & (p3 - 1);
        const int k3 = floc >> lp3;
        if (k3 >= 1 && k3 < nk3) {
          const float* pa3 = &sc[k3][k3];          // C(k3 -> k3+i)
          const float* pb3 = &sc[k3 + wn][k3 + 1]; // C(k3+wn -> k3+1+i)
          const int ch3 = wn >> lp3;
          const int i0 = q3 * ch3;
          const int ntrip = ((q3 == p3 - 1) ? wn : i0 + ch3) - i0;
          auto val = [&](int i) { return pa3[i] + pb3[i]; };
          float r = lse_run(val, i0, ntrip, NEGF, false, lp3);
          if (q3 == 0) ssw[wn * S + k3] = r;
        }
      } else {               // enrich: one thread per (typ, row); coalesced SSW
        const int rows1 = nk3 - 1;
        const int rowlen = wn - 1;
        const int rlP2 = rowlen | 1;
        const int typ = floc >> 7, kk2 = floc & 127;
        if (kk2 < rows1 && rowlen > 0) {
          const int kr = kk2 + 1;
          float* st = &stage[(typ * rows1 + kk2) * rlP2];
          if (typ == 0) {
            // ir row k: += SSW[wn-1-i][kr+1+i] (anti-diagonal; coalesced in k)
            const float* pw_ = ssw + (wn - 1) * S + (kr + 1);
#pragma unroll 4
            for (int i = 0; i < rowlen; ++i) st[i] += pw_[i * (1 - S)];
          } else {
            // il row k: += SSW[1+i][kr] (column; coalesced in k)
            const float* pw_ = ssw + S + kr;
#pragma unroll 4
            for (int i = 0; i < rowlen; ++i) st[i] += pw_[i * S];
          }
        }
      }
      spk_off += 2 * (S - wn - 1) * ((wn - 1) | 1);
    }
    __syncthreads();   // B3: stage(w+1) complete
  }
}

// Gather score: masked arc scores + positive-sibling scores, count mask.
__global__ __launch_bounds__(256) void score_kernel(
    const float* __restrict__ arc, const float* __restrict__ sib,
    const unsigned char* __restrict__ mask, const int* __restrict__ arcs,
    const int* __restrict__ sibs, int B)
{
  __shared__ bool bytes_sh;
  if (threadIdx.x == 0) {
    int c = 0;
    for (int i = 0; i < S; ++i) c += (mask[i] != 0);
    bytes_sh = (c >= 64);
  }
  __syncthreads();
  const bool bytes = bytes_sh;

  const int total = B * S * S;
  int tid = blockIdx.x * blockDim.x + threadIdx.x;
  float sum = 0.f, cnt = 0.f;
  for (int e = tid; e < total; e += gridDim.x * blockDim.x) {
    int sv = sibs[e];
    if (sv > 0) sum += sib[(size_t)e * S + sv];
    if ((e & (S - 1)) == 0) {           // once per (b,i)
      int bi = e >> 7;
      if (mask_at(mask, bi, bytes)) { sum += arc[(size_t)bi * S + arcs[bi]]; cnt += 1.f; }
    }
  }
  __shared__ float rs[256], rc[256];
  rs[threadIdx.x] = sum; rc[threadIdx.x] = cnt;
  __syncthreads();
  for (int off = 128; off; off >>= 1) {
    if (threadIdx.x < off) {
      rs[threadIdx.x] += rs[threadIdx.x + off];
      rc[threadIdx.x] += rc[threadIdx.x + off];
    }
    __syncthreads();
  }
  if (threadIdx.x == 0) {
    g_partials[blockIdx.x * 2]     = rs[0];
    g_partials[blockIdx.x * 2 + 1] = rc[0];
  }
}

__global__ __launch_bounds__(256) void final_kernel(int B, float* __restrict__ out)
{
  __shared__ float rs[256], rc[256];
  int t = threadIdx.x;
  float v = -g_partials[t * 2];
  float c = g_partials[t * 2 + 1];
  if (t < B) v += g_logZ[t];
  rs[t] = v; rc[t] = c;
  __syncthreads();
  for (int off = 128; off; off >>= 1) {
    if (t < off) { rs[t] += rs[t + off]; rc[t] += rc[t + off]; }
    __syncthreads();
  }
  if (t == 0) out[0] = rs[0] / rc[0];   // (logZ - score) / mask.sum()
}

extern "C" void kernel_launch(void* const* d_in, const int* in_sizes, int n_in,
                              void* d_out, int out_size, void* d_ws, size_t ws_size,
                              hipStream_t stream) {
  const float* s_arc = (const float*)d_in[0];
  const float* s_sib = (const float*)d_in[1];
  const unsigned char* mask = (const unsigned char*)d_in[2];
  const int* arcs = (const int*)d_in[3];
  const int* sibs = (const int*)d_in[4];
  int B = in_sizes[0] / (S * S);
  if (B > MAXB) B = MAXB;

  pack_kernel<<<dim3(B * 126), dim3(256), 0, stream>>>(s_sib);
  score_kernel<<<dim3(256), dim3(256), 0, stream>>>(s_arc, s_sib, mask, arcs, sibs, B);
  dp_kernel<<<dim3(B), dim3(NT), 0, stream>>>(s_arc, mask);
  final_kernel<<<dim3(1), dim3(256), 0, stream>>>(B, (float*)d_out);
}